// Round 11
// baseline (309.827 us; speedup 1.0000x reference)
//
#include <hip/hip_runtime.h>

#define OUT_F 11008
#define IN_F  4096
#define NBATCH 8
#define TOTAL (OUT_F * IN_F)
#define PACK_WORDS (TOTAL / 8)        // 5,636,096 uint32 (8 nibbles each)
#define PSTRIDE (IN_F / 8)            // 512 packed words per row

#define RB 16                         // rows per block (pass 2)
#define BLOCK 256
#define COLS 2048                     // cols per block chunk (pass 2)
#define CHUNKS (IN_F / COLS)          // 2
#define GPC (COLS / 128)              // 16 groups per row-chunk

__device__ __forceinline__ unsigned short bf16_rne(float f) {
    unsigned int b = __float_as_uint(f);
    b += 0x7FFFu + ((b >> 16) & 1u);
    return (unsigned short)(b >> 16);
}
__device__ __forceinline__ float bf16_up(unsigned short u) {
    return __uint_as_float(((unsigned int)u) << 16);
}

// ---- Pass 1: pure stream. Read 180 MB idx, write 22.5 MB packed nibbles.
// Structurally identical to a copy: no gathers, no FMAs, no LDS, no barriers.
__global__ __launch_bounds__(BLOCK) void pack_kernel(
    const int* __restrict__ widx, unsigned int* __restrict__ packed)
{
    const size_t stride = (size_t)gridDim.x * BLOCK;
    size_t w = (size_t)blockIdx.x * BLOCK + threadIdx.x;
#pragma unroll 1
    for (; w < PACK_WORDS; w += stride) {
        const int4 a = *reinterpret_cast<const int4*>(widx + 8 * w);
        const int4 b = *reinterpret_cast<const int4*>(widx + 8 * w + 4);
        const unsigned int p =
            (unsigned int)(a.x & 15)        | ((unsigned int)(a.y & 15) << 4)  |
            ((unsigned int)(a.z & 15) << 8) | ((unsigned int)(a.w & 15) << 12) |
            ((unsigned int)(b.x & 15) << 16)| ((unsigned int)(b.y & 15) << 20) |
            ((unsigned int)(b.z & 15) << 24)| ((unsigned int)(b.w & 15) << 28);
        packed[w] = p;
    }
}

// ---- Pass 2: R9's proven skeleton, idx traffic 8x smaller (and L2/L3-hot).
__global__ __launch_bounds__(BLOCK) void gemv_kernel(
    const float* __restrict__ x,              // [8, 4096]
    const unsigned int* __restrict__ packed,  // [11008, 512] nibbles
    const float* __restrict__ lut,            // [352256, 16] f32
    const float* __restrict__ bias,           // [11008]
    float* __restrict__ out)                  // [8, 11008], zeroed
{
    __shared__ unsigned short xS[NBATCH * COLS];   // 32 KB bf16
    __shared__ float lutS[RB * GPC * 16];          // 16 KB

    const int tid   = threadIdx.x;
    const int lane  = tid & 63;
    const int wave  = tid >> 6;
    const int rowG  = blockIdx.x >> 1;
    const int chunk = blockIdx.x & 1;
    const int o0    = rowG * RB;
    const int c0    = chunk * COLS;
    const int wcol  = wave * 512;                  // wave's 512-col window

    // stage x chunk as bf16 (RNE), 8 x 2048 -> 32 KB (verified R10, absmax 0.031)
#pragma unroll
    for (int i = 0; i < 16; ++i) {
        const int j  = tid + i * BLOCK;
        const int m  = j >> 9;
        const int cc = (j & 511) * 4;
        const float4 v = *reinterpret_cast<const float4*>(x + m * IN_F + c0 + cc);
        ushort4 p;
        p.x = bf16_rne(v.x); p.y = bf16_rne(v.y);
        p.z = bf16_rne(v.z); p.w = bf16_rne(v.w);
        *reinterpret_cast<ushort4*>(xS + m * COLS + cc) = p;
    }
    // stage lut slice: 16 rows x 16 groups x 16 entries
#pragma unroll
    for (int i = 0; i < 4; ++i) {
        const int j  = tid + i * BLOCK;
        const int r  = j >> 6;
        const int w4 = (j & 63) * 4;
        *reinterpret_cast<float4*>(lutS + r * (GPC * 16) + w4) =
            *reinterpret_cast<const float4*>(
                lut + (size_t)(o0 + r) * 512 + chunk * 256 + w4);
    }
    __syncthreads();

    float acc[RB][NBATCH];
#pragma unroll
    for (int r = 0; r < RB; ++r)
#pragma unroll
        for (int m = 0; m < NBATCH; ++m) acc[r][m] = 0.0f;

    const int gb   = ((wcol + 8 * lane) >> 7) * 16;   // lane's 8 cols: one group
    const int xoff = wcol + 8 * lane;

#pragma unroll
    for (int it = 0; it < 4; ++it) {
        const int rs = it * 4;

        // 4 packed words (16 B/lane/iter vs R9's 64 B)
        unsigned int pw[4];
#pragma unroll
        for (int j = 0; j < 4; ++j)
            pw[j] = packed[(size_t)(o0 + rs + j) * PSTRIDE + chunk * 256
                           + (wcol >> 3) + lane];

        // decode 8 nibbles/row -> LDS gathers (16-entry group = 16 banks)
        float w[4][8];
#pragma unroll
        for (int j = 0; j < 4; ++j) {
            const float* lr = lutS + (rs + j) * (GPC * 16) + gb;
#pragma unroll
            for (int k = 0; k < 8; ++k)
                w[j][k] = lr[(pw[j] >> (4 * k)) & 15];
        }

        // FMAs: 8 cols x 4 rows x 8 batches, all static indexing
#pragma unroll
        for (int m = 0; m < NBATCH; ++m) {
            const ushort4 xa = *reinterpret_cast<const ushort4*>(xS + m * COLS + xoff);
            const ushort4 xb = *reinterpret_cast<const ushort4*>(xS + m * COLS + xoff + 4);
            const float x0 = bf16_up(xa.x), x1 = bf16_up(xa.y);
            const float x2 = bf16_up(xa.z), x3 = bf16_up(xa.w);
            const float x4 = bf16_up(xb.x), x5 = bf16_up(xb.y);
            const float x6 = bf16_up(xb.z), x7 = bf16_up(xb.w);
#pragma unroll
            for (int j = 0; j < 4; ++j) {
                float a = acc[rs + j][m];
                a = fmaf(w[j][0], x0, a);
                a = fmaf(w[j][1], x1, a);
                a = fmaf(w[j][2], x2, a);
                a = fmaf(w[j][3], x3, a);
                a = fmaf(w[j][4], x4, a);
                a = fmaf(w[j][5], x5, a);
                a = fmaf(w[j][6], x6, a);
                a = fmaf(w[j][7], x7, a);
                acc[rs + j][m] = a;
            }
        }
    }

    // epilogue: R9/R10-verified packed wave reduce + direct atomics
#pragma unroll
    for (int gq = 0; gq < 4; ++gq) {
        float f[4][NBATCH];
#pragma unroll
        for (int r = 0; r < 4; ++r)
#pragma unroll
            for (int m = 0; m < NBATCH; ++m) {
                const float a = acc[gq * 4 + r][m];
                f[r][m] = a + __shfl_xor(a, 32, 64);
            }
        float e[16];
#pragma unroll
        for (int r = 0; r < 4; ++r)
#pragma unroll
            for (int q = 0; q < 4; ++q)
                e[r * 4 + q] = (lane < 32) ? f[r][2 * q] : f[r][2 * q + 1];
#pragma unroll
        for (int off = 16; off >= 1; off >>= 1)
#pragma unroll
            for (int p = 0; p < 16; ++p)
                e[p] += __shfl_xor(e[p], off, 64);

        const int p = lane & 15;
        float v = 0.0f;
#pragma unroll
        for (int pp = 0; pp < 16; ++pp)
            if (p == pp) v = e[pp];               // static cndmask chain (R5 lesson)

        const bool lo = (lane < 16);
        const bool hi = (lane >= 32) && (lane < 48);
        if (lo || hi) {
            const int r   = p >> 2;
            const int m   = 2 * (p & 3) + (lo ? 0 : 1);
            const int row = o0 + gq * 4 + r;
            if (chunk == 0 && wave == 0) v += bias[row];   // exactly once
            atomicAdd(out + (size_t)m * OUT_F + row, v);
        }
    }
}

extern "C" void kernel_launch(void* const* d_in, const int* in_sizes, int n_in,
                              void* d_out, int out_size, void* d_ws, size_t ws_size,
                              hipStream_t stream) {
    const float* x    = (const float*)d_in[0];
    const int*   widx = (const int*)d_in[1];
    const float* lut  = (const float*)d_in[2];
    const float* bias = (const float*)d_in[3];
    float* out = (float*)d_out;
    unsigned int* packed = (unsigned int*)d_ws;

    hipMemsetAsync(out, 0, (size_t)out_size * sizeof(float), stream);
    pack_kernel<<<4096, BLOCK, 0, stream>>>(widx, packed);
    gemv_kernel<<<(OUT_F / RB) * CHUNKS, BLOCK, 0, stream>>>(
        x, packed, lut, bias, out);
}

// Round 12
// 259.798 us; speedup vs baseline: 1.1926x; 1.1926x over previous
//
#include <hip/hip_runtime.h>

#define OUT_F 11008
#define IN_F  4096
#define NBATCH 8
#define R 4                      // output rows per wave
#define BLOCK 64                 // one wave per block
#define NGR 32                   // groups per row = IN_F/128
#define KITERS (IN_F / (4 * BLOCK))   // 16 iters: lane covers 4 cols per iter

// ext_vector aliases: __builtin_nontemporal_load needs scalar/vector types
typedef int   vint4   __attribute__((ext_vector_type(4)));
typedef float vfloat4 __attribute__((ext_vector_type(4)));

// R7 structure (best: ~79us kernel) + NON-TEMPORAL streaming reads.
// Theory C: the harness's 721MB d_ws poison-fill leaves all of L3 dirty;
// normal widx reads must evict+writeback a dirty line per miss (~250MB
// hidden write traffic) -> every R3-R11 kernel capped at ~2.4-2.6 TB/s.
// nt loads don't allocate -> no eviction tax on the 180MB idx stream.
__global__ __launch_bounds__(BLOCK) void pal_linear_kernel(
    const float* __restrict__ x,        // [8, 4096]
    const int*   __restrict__ widx,     // [11008*4096] in [0,16)
    const float* __restrict__ lut,      // [352256, 16] f32 on device
    const float* __restrict__ bias,     // [11008]
    float* __restrict__ out)            // [8, 11008]
{
    __shared__ float lutS[R * NGR * 16];   // 8 KB wave-private slice

    const int tid = threadIdx.x;           // lane 0..63
    const int o0  = blockIdx.x * R;

    // stage the tile's LUT slice (nt: read-once stream, don't pollute/evict)
    {
        const vfloat4* src = reinterpret_cast<const vfloat4*>(lut + (size_t)o0 * NGR * 16);
        float4* dst = reinterpret_cast<float4*>(lutS);
#pragma unroll
        for (int i = 0; i < (R * NGR * 16 / 4) / BLOCK; ++i) {   // 8 iters
            const vfloat4 v = __builtin_nontemporal_load(src + tid + i * BLOCK);
            dst[tid + i * BLOCK] = make_float4(v.x, v.y, v.z, v.w);
        }
    }
    __syncthreads();

    float acc[R][NBATCH];
#pragma unroll
    for (int r = 0; r < R; ++r)
#pragma unroll
        for (int m = 0; m < NBATCH; ++m) acc[r][m] = 0.0f;

    vint4 idx_cur[R], idx_nxt[R];
#pragma unroll
    for (int r = 0; r < R; ++r)
        idx_cur[r] = __builtin_nontemporal_load(
            reinterpret_cast<const vint4*>(widx + (size_t)(o0 + r) * IN_F + 4 * tid));

#pragma unroll 1
    for (int k = 0; k < KITERS; ++k) {
        const int c = 4 * (tid + BLOCK * k);

        // 1) x loads (L2-hot, cached normally — x IS reused across blocks)
        float4 xv[NBATCH];
#pragma unroll
        for (int m = 0; m < NBATCH; ++m)
            xv[m] = *reinterpret_cast<const float4*>(x + m * IN_F + c);

        // 2) nt idx prefetch — no L3 allocate, no dirty-line eviction
        if (k + 1 < KITERS) {
#pragma unroll
            for (int r = 0; r < R; ++r)
                idx_nxt[r] = __builtin_nontemporal_load(
                    reinterpret_cast<const vint4*>(
                        widx + (size_t)(o0 + r) * IN_F + c + 4 * BLOCK));
        }

        // 3) LDS gathers with current indices
        const int gcol = (c >> 7) * 16;
        float w[R][4];
#pragma unroll
        for (int r = 0; r < R; ++r) {
            const float* lr = lutS + r * (NGR * 16) + gcol;
            w[r][0] = lr[idx_cur[r].x];
            w[r][1] = lr[idx_cur[r].y];
            w[r][2] = lr[idx_cur[r].z];
            w[r][3] = lr[idx_cur[r].w];
        }

        // 4) FMAs (fully unrolled, all register-resident)
#pragma unroll
        for (int m = 0; m < NBATCH; ++m)
#pragma unroll
            for (int r = 0; r < R; ++r) {
                float a = acc[r][m];
                a = fmaf(w[r][0], xv[m].x, a);
                a = fmaf(w[r][1], xv[m].y, a);
                a = fmaf(w[r][2], xv[m].z, a);
                a = fmaf(w[r][3], xv[m].w, a);
                acc[r][m] = a;
            }

#pragma unroll
        for (int r = 0; r < R; ++r) idx_cur[r] = idx_nxt[r];
    }

    // full-wave butterfly reduce
#pragma unroll
    for (int r = 0; r < R; ++r)
#pragma unroll
        for (int m = 0; m < NBATCH; ++m) {
            float v = acc[r][m];
#pragma unroll
            for (int off = 32; off >= 1; off >>= 1)
                v += __shfl_xor(v, off, 64);
            acc[r][m] = v;
        }

    // static select (R5 lesson: no runtime indexing of register arrays)
    float v = 0.0f;
#pragma unroll
    for (int r = 0; r < R; ++r)
#pragma unroll
        for (int m = 0; m < NBATCH; ++m)
            if (tid == r * NBATCH + m) v = acc[r][m];

    if (tid < R * NBATCH) {
        const int r = tid >> 3;
        const int m = tid & 7;
        out[(size_t)m * OUT_F + (o0 + r)] = v + bias[o0 + r];
    }
}

extern "C" void kernel_launch(void* const* d_in, const int* in_sizes, int n_in,
                              void* d_out, int out_size, void* d_ws, size_t ws_size,
                              hipStream_t stream) {
    const float* x    = (const float*)d_in[0];
    const int*   widx = (const int*)d_in[1];
    const float* lut  = (const float*)d_in[2];
    const float* bias = (const float*)d_in[3];
    float* out = (float*)d_out;

    pal_linear_kernel<<<OUT_F / R, BLOCK, 0, stream>>>(x, widx, lut, bias, out);
}